// Round 2
// baseline (420.987 us; speedup 1.0000x reference)
//
#include <hip/hip_runtime.h>

// ---------------------------------------------------------------------------
// AttentionHead: B=4, C=256, N=4096, QK=64. Column-softmax attention.
// R14: k_attn rebuilt zero-LDS / zero-barrier. Swapped QK^T (S^T = K·Q^T,
// 32x32x16 MFMA) makes P lane-local; cvt_pk_bf16 + permlane32_swap converts
// S^T output (4 j/lane) into PV A-fragments (8 j/lane) fully in-register.
// rs[j] is folded into V (k_colsum epilogue scales Vc in place), so
// P = exp(S/8) elementwise. Wave = 32i x 64c, block = 4 waves (128i),
// grid = 32 ib x 4 cb x 4 b = 512 linear (b = id&3 XCD batch-pin kept).
// S^T recomputed per c-block (4x) - trades cheap MFMA/exp for zero LDS
// traffic (R12 k_attn was LDS-pipe-bound: 512 ds_read_b128 + scalar u16
// writes + 8.4M conflict cycles per block-iter vs 770 MFMA cycles).
// Other kernels identical to R12 (the 284.8us best).
// Workspace: 29,884,416 bytes (rs slot now unused).
// ---------------------------------------------------------------------------

typedef unsigned short u16;
typedef __attribute__((ext_vector_type(8))) unsigned short ushort8;
typedef __attribute__((ext_vector_type(8))) __bf16 bf16x8;
typedef __attribute__((ext_vector_type(4))) float f32x4;
typedef __attribute__((ext_vector_type(16))) float f32x16;
typedef __attribute__((ext_vector_type(4))) unsigned int uint4v;

#define MFMA16(a, b, c) __builtin_amdgcn_mfma_f32_16x16x32_bf16((a), (b), (c), 0, 0, 0)
#define MFMA32(a, b, c) __builtin_amdgcn_mfma_f32_32x32x16_bf16((a), (b), (c), 0, 0, 0)

// v_permlane32_swap_b32: a.hi32lanes <-> b.lo32lanes (in place, both updated)
#define PLSWAP(a, b) asm volatile("v_permlane32_swap_b32 %0, %1" : "+v"(a), "+v"(b))

__device__ __forceinline__ u16 f2bf(float f) {
  unsigned int u = __builtin_bit_cast(unsigned int, f);
  u += 0x7FFFu + ((u >> 16) & 1u);  // round-to-nearest-even
  return (u16)(u >> 16);
}

__device__ __forceinline__ float bf2f(u16 v) {
  return __builtin_bit_cast(float, (unsigned int)v << 16);
}

__device__ __forceinline__ unsigned int cvtpk(float lo, float hi) {
  unsigned int r;
  asm volatile("v_cvt_pk_bf16_f32 %0, %1, %2" : "=v"(r) : "v"(lo), "v"(hi));
  return r;
}

__device__ __forceinline__ bf16x8 mk8(unsigned int w0, unsigned int w1,
                                      unsigned int w2, unsigned int w3) {
  uint4v u = {w0, w1, w2, w3};
  return __builtin_bit_cast(bf16x8, u);
}

__device__ __forceinline__ bf16x8 ld8(const u16* p) {
  return __builtin_bit_cast(bf16x8, *reinterpret_cast<const ushort8*>(p));
}

__device__ __forceinline__ f32x4 fz4() {
  f32x4 z = {0.f, 0.f, 0.f, 0.f};
  return z;
}

__device__ __forceinline__ f32x16 fz16() {
  f32x16 z = {0.f, 0.f, 0.f, 0.f, 0.f, 0.f, 0.f, 0.f,
              0.f, 0.f, 0.f, 0.f, 0.f, 0.f, 0.f, 0.f};
  return z;
}

// ---- convert all weight matrices fp32 -> bf16 (one launch) ----------------
__global__ __launch_bounds__(256) void k_convert(
    const float* __restrict__ wq, const float* __restrict__ wk,
    const float* __restrict__ wv, const float* __restrict__ w1,
    const float* __restrict__ w2, u16* __restrict__ dq, u16* __restrict__ dk,
    u16* __restrict__ dv, u16* __restrict__ d1, u16* __restrict__ d2) {
  int i = blockIdx.x * 256 + threadIdx.x;
  if (i < 16384)       dq[i]           = f2bf(wq[i]);
  else if (i < 32768)  dk[i - 16384]   = f2bf(wk[i - 16384]);
  else if (i < 98304)  dv[i - 32768]   = f2bf(wv[i - 32768]);
  else if (i < 163840) d1[i - 98304]   = f2bf(w1[i - 98304]);
  else                 d2[i - 163840]  = f2bf(w2[i - 163840]);
}

// ---- x [b][256][4096] fp32 -> xT [b][4096][256] bf16 (LDS-tiled) ----------
__global__ __launch_bounds__(256) void k_transpose(const float* __restrict__ x,
                                                   u16* __restrict__ xT) {
  __shared__ float t[64][65];
  int n0 = blockIdx.x * 64, c0 = blockIdx.y * 64, b = blockIdx.z;
  int tx = threadIdx.x & 63, ty = threadIdx.x >> 6;
  const float* xb = x + ((size_t)b * 256 + c0) * 4096 + n0;
#pragma unroll
  for (int i = 0; i < 64; i += 4) t[ty + i][tx] = xb[(size_t)(ty + i) * 4096 + tx];
  __syncthreads();
  u16* xo = xT + ((size_t)b * 4096 + n0) * 256 + c0;
#pragma unroll
  for (int i = 0; i < 64; i += 4) xo[(size_t)(ty + i) * 256 + tx] = f2bf(t[tx][ty + i]);
}

// ---- fused QKV projection: 32-pos tiles, grid 512 linear (b = id&3) -------
__global__ __launch_bounds__(256) void k_proj(
    const u16* __restrict__ xT, const u16* __restrict__ wq,
    const u16* __restrict__ wk, const u16* __restrict__ wv,
    const float* __restrict__ bQ, const float* __restrict__ bK,
    const float* __restrict__ bV, const float* __restrict__ PE,
    u16* __restrict__ Qt, u16* __restrict__ Kt, u16* __restrict__ Vc) {
  int b = blockIdx.x & 3, n0 = (blockIdx.x >> 2) * 32;
  int lane = threadIdx.x & 63, wid = threadIdx.x >> 6;
  int l15 = lane & 15, g = lane >> 4;
  const u16* xrow = xT + ((size_t)b * 4096 + n0) * 256;

  f32x4 aq[2], ak[2], av[4][2];
#pragma unroll
  for (int m = 0; m < 2; ++m) { aq[m] = fz4(); ak[m] = fz4(); }
#pragma unroll
  for (int m = 0; m < 4; ++m)
#pragma unroll
    for (int n = 0; n < 2; ++n) av[m][n] = fz4();

  for (int kk = 0; kk < 8; ++kk) {
    int ko = kk * 32 + g * 8;
    bf16x8 xa[2];
#pragma unroll
    for (int m = 0; m < 2; ++m) xa[m] = ld8(xrow + (16 * m + l15) * 256 + ko);
    bf16x8 fq = ld8(wq + (16 * wid + l15) * 256 + ko);
    bf16x8 fk = ld8(wk + (16 * wid + l15) * 256 + ko);
#pragma unroll
    for (int m = 0; m < 2; ++m) {
      aq[m] = MFMA16(xa[m], fq, aq[m]);
      ak[m] = MFMA16(xa[m], fk, ak[m]);
    }
    bf16x8 fv[4];
#pragma unroll
    for (int m = 0; m < 4; ++m) fv[m] = ld8(wv + (64 * wid + 16 * m + l15) * 256 + ko);
#pragma unroll
    for (int m = 0; m < 4; ++m)
#pragma unroll
      for (int n = 0; n < 2; ++n) av[m][n] = MFMA16(fv[m], xa[n], av[m][n]);
  }

  int o = 16 * wid + l15;
#pragma unroll
  for (int m = 0; m < 2; ++m)
#pragma unroll
    for (int r = 0; r < 4; ++r) {
      int pos = n0 + 16 * m + 4 * g + r;
      float pe = PE[o * 4096 + pos];
      Qt[((size_t)b * 4096 + pos) * 64 + o] = f2bf(aq[m][r] + bQ[o] + pe);
      Kt[((size_t)b * 4096 + pos) * 64 + o] = f2bf(ak[m][r] + bK[o] + pe);
    }
#pragma unroll
  for (int m = 0; m < 4; ++m) {
    int ov = 64 * wid + 16 * m + 4 * g;
#pragma unroll
    for (int r = 0; r < 4; ++r) {
      float bvv = bV[ov + r];
#pragma unroll
      for (int n = 0; n < 2; ++n) {
        int pos = n0 + 16 * n + l15;
        Vc[((size_t)b * 256 + ov + r) * 4096 + pos] = f2bf(av[m][n][r] + bvv);
      }
    }
  }
}

// ---- pass 1: column sums + fold 1/colsum into V, 512 thr, grid 256 --------
// R12 body; epilogue now scales Vc[:, j0..j0+63] in place by rs[j] so k_attn
// needs no per-element rs multiply (P = exp(S/8) purely elementwise).
__global__ __launch_bounds__(512) void k_colsum(const u16* __restrict__ Qt,
                                                const u16* __restrict__ Kt,
                                                u16* __restrict__ Vc) {
  __shared__ float ps[8][16];
  __shared__ float rsf[64];
  int b = blockIdx.x & 3, j0 = (blockIdx.x >> 2) * 64;
  int lane = threadIdx.x & 63, wid = threadIdx.x >> 6;  // wid in [0,8)
  int l15 = lane & 15, g = lane >> 4;
  int w4 = wid & 3, ihalf = wid >> 2;
  const u16* qb = Qt + (size_t)b * 262144;
  const u16* kb = Kt + (size_t)b * 262144;
  int j = j0 + 16 * w4 + l15;
  bf16x8 fk[2];
#pragma unroll
  for (int h = 0; h < 2; ++h) fk[h] = ld8(kb + j * 64 + h * 32 + 8 * g);
  float part = 0.f;
  for (int i0 = ihalf * 2048; i0 < ihalf * 2048 + 2048; i0 += 64) {
    f32x4 acc[4];
#pragma unroll
    for (int m = 0; m < 4; ++m) acc[m] = fz4();
#pragma unroll
    for (int m = 0; m < 4; ++m) {
      const u16* qr = qb + (i0 + 16 * m + l15) * 64;
      acc[m] = MFMA16(ld8(qr + 8 * g), fk[0], acc[m]);
      acc[m] = MFMA16(ld8(qr + 32 + 8 * g), fk[1], acc[m]);
    }
#pragma unroll
    for (int m = 0; m < 4; ++m)
#pragma unroll
      for (int r = 0; r < 4; ++r) part += __expf(acc[m][r] * 0.125f);
  }
  part += __shfl_xor(part, 16);
  part += __shfl_xor(part, 32);
  if (g == 0) ps[wid][l15] = part;
  __syncthreads();
  if (threadIdx.x < 64) {
    int jj = threadIdx.x;
    rsf[jj] = 1.0f / (ps[jj >> 4][jj & 15] + ps[(jj >> 4) + 4][jj & 15]);
  }
  __syncthreads();
  // scale V columns j0..j0+63 across all 256 channels (2 threads / channel)
  {
    int c = threadIdx.x >> 1, half = threadIdx.x & 1;
    u16* vp = Vc + ((size_t)b * 256 + c) * 4096 + j0 + half * 32;
#pragma unroll
    for (int q = 0; q < 4; ++q) {
      ushort8 v = *reinterpret_cast<const ushort8*>(vp + q * 8);
      ushort8 ov;
#pragma unroll
      for (int e = 0; e < 8; ++e)
        ov[e] = f2bf(bf2f(v[e]) * rsf[half * 32 + q * 8 + e]);
      *reinterpret_cast<ushort8*>(vp + q * 8) = ov;
    }
  }
}

// ---- pass 2: attention, zero-LDS zero-barrier, 256 thr, grid 512 ----------
// Wave owns 32i x 64c. Per 32-j tile: S^T = K_j . Q_i^T (4 MFMA32, d=64),
// exp in-register, cvt_pk+permlane32_swap -> PV A-frags, 4 PV MFMA32.
// S^T output (col=i=lane&31) matches PV-A (row=i=lane&31); j moves from
// (r&3)+8*(r>>2)+4*hi layout to 8*hi+e via the half-swap.
__global__ __launch_bounds__(256) void k_attn(
    const u16* __restrict__ Qt, const u16* __restrict__ Kt,
    const u16* __restrict__ Vc, u16* __restrict__ attT) {
  int id = blockIdx.x;
  int b = id & 3;
  int r2 = id >> 2;                  // 0..127
  int ib = r2 & 31, cb = r2 >> 5;    // same-XCD neighbors share cb (V stream)
  int i0 = ib * 128, c0 = cb * 64;
  int lane = threadIdx.x & 63, wid = threadIdx.x >> 6;  // 4 waves, i-split
  int l31 = lane & 31, hi = lane >> 5;
  int iw = i0 + wid * 32;

  const u16* qb = Qt + (size_t)b * 262144;
  const u16* kb = Kt + (size_t)b * 262144;
  const u16* vb = Vc + (size_t)b * 1048576;

  // Q B-fragments for this wave's 32 i rows (held for entire j sweep)
  bf16x8 aq[4];
#pragma unroll
  for (int dc = 0; dc < 4; ++dc)
    aq[dc] = ld8(qb + (iw + l31) * 64 + dc * 16 + hi * 8);

  f32x16 o0 = fz16(), o1 = fz16();  // out tiles: c0+l31 / c0+32+l31

  const u16* krow = kb + l31 * 64 + hi * 8;
  const u16* v0 = vb + (size_t)(c0 + l31) * 4096 + hi * 8;
  const u16* v1 = vb + (size_t)(c0 + 32 + l31) * 4096 + hi * 8;

#pragma unroll 2
  for (int jb = 0; jb < 4096; jb += 32) {
    // K A-fragments: rows j = jb + l31, d chunks of 16
    bf16x8 ka0 = ld8(krow + (size_t)jb * 64);
    bf16x8 ka1 = ld8(krow + (size_t)jb * 64 + 16);
    bf16x8 ka2 = ld8(krow + (size_t)jb * 64 + 32);
    bf16x8 ka3 = ld8(krow + (size_t)jb * 64 + 48);
    // V B-fragments (rs pre-folded): two 16-j chunks x two c tiles
    bf16x8 fva0 = ld8(v0 + jb);
    bf16x8 fvb0 = ld8(v1 + jb);
    bf16x8 fva1 = ld8(v0 + jb + 16);
    bf16x8 fvb1 = ld8(v1 + jb + 16);

    // S^T[j][i] for 32j x 32i, k = d = 64
    f32x16 s = MFMA32(ka0, aq[0], fz16());
    s = MFMA32(ka1, aq[1], s);
    s = MFMA32(ka2, aq[2], s);
    s = MFMA32(ka3, aq[3], s);

#pragma unroll
    for (int r = 0; r < 16; ++r) s[r] = __expf(s[r] * 0.125f);

    // chunk0 (j 0..15): lane needs j = 8*hi + e
    unsigned int a0 = cvtpk(s[0], s[1]), a1 = cvtpk(s[2], s[3]);
    unsigned int b0 = cvtpk(s[4], s[5]), b1 = cvtpk(s[6], s[7]);
    PLSWAP(a0, b0);
    PLSWAP(a1, b1);
    bf16x8 pa0 = mk8(a0, a1, b0, b1);
    // chunk1 (j 16..31)
    unsigned int e0 = cvtpk(s[8], s[9]), e1 = cvtpk(s[10], s[11]);
    unsigned int f0 = cvtpk(s[12], s[13]), f1 = cvtpk(s[14], s[15]);
    PLSWAP(e0, f0);
    PLSWAP(e1, f1);
    bf16x8 pa1 = mk8(e0, e1, f0, f1);

    o0 = MFMA32(pa0, fva0, o0);
    o1 = MFMA32(pa0, fvb0, o1);
    o0 = MFMA32(pa1, fva1, o0);
    o1 = MFMA32(pa1, fvb1, o1);
  }

#pragma unroll
  for (int r = 0; r < 16; ++r) {
    int i = iw + (r & 3) + 8 * (r >> 2) + 4 * hi;
    size_t base = ((size_t)b * 4096 + i) * 256;
    attT[base + c0 + l31] = f2bf(o0[r]);
    attT[base + c0 + 32 + l31] = f2bf(o1[r]);
  }
}

// ---- fused MLP, 512 thr, grid 256 linear (b = id&3) -----------------------
__global__ __launch_bounds__(512) void k_mlp(
    const u16* __restrict__ attT, const u16* __restrict__ w1,
    const float* __restrict__ b1, const u16* __restrict__ w2,
    const float* __restrict__ b2, const float* __restrict__ x,
    float* __restrict__ out) {
  __shared__ u16 hdnS[64][264];
  int b = blockIdx.x & 3, n0 = (blockIdx.x >> 2) * 64;
  int lane = threadIdx.x & 63, wid = threadIdx.x >> 6;  // wid in [0,8)
  int l15 = lane & 15, g = lane >> 4;
  const u16* arow = attT + ((size_t)b * 4096 + n0) * 256;

  // stage 1: hdn = mish(att @ W1^T + b1) -> LDS; wave strip = 32 h-channels
  {
    f32x4 acc[4][2];
#pragma unroll
    for (int m = 0; m < 4; ++m)
#pragma unroll
      for (int n = 0; n < 2; ++n) acc[m][n] = fz4();
    for (int kk = 0; kk < 8; ++kk) {
      int ko = kk * 32 + 8 * g;
      bf16x8 am[4], bn[2];
#pragma unroll
      for (int m = 0; m < 4; ++m) am[m] = ld8(arow + (16 * m + l15) * 256 + ko);
#pragma unroll
      for (int n = 0; n < 2; ++n) bn[n] = ld8(w1 + (32 * wid + 16 * n + l15) * 256 + ko);
#pragma unroll
      for (int m = 0; m < 4; ++m)
#pragma unroll
        for (int n = 0; n < 2; ++n) acc[m][n] = MFMA16(am[m], bn[n], acc[m][n]);
    }
#pragma unroll
    for (int m = 0; m < 4; ++m)
#pragma unroll
      for (int n = 0; n < 2; ++n) {
        int hh = 32 * wid + 16 * n + l15;
        float bb = b1[hh];
#pragma unroll
        for (int r = 0; r < 4; ++r) {
          float v = acc[m][n][r] + bb;
          float sp = (v > 15.f) ? v : __logf(1.f + __expf(v));
          float e2 = __expf(-2.f * sp);
          float th = (1.f - e2) / (1.f + e2);
          hdnS[16 * m + 4 * g + r][hh] = f2bf(v * th);
        }
      }
  }
  __syncthreads();

  // stage 2: out = hdn @ W2^T + b2 + x; wave strip = 32 o-channels
  {
    f32x4 acc[2][4];
#pragma unroll
    for (int m = 0; m < 2; ++m)
#pragma unroll
      for (int n = 0; n < 4; ++n) acc[m][n] = fz4();
    for (int kk = 0; kk < 8; ++kk) {
      int ko = kk * 32 + 8 * g;
      bf16x8 am[2], bn[4];
#pragma unroll
      for (int m = 0; m < 2; ++m) am[m] = ld8(w2 + (32 * wid + 16 * m + l15) * 256 + ko);
#pragma unroll
      for (int n = 0; n < 4; ++n) bn[n] = ld8(&hdnS[16 * n + l15][ko]);
#pragma unroll
      for (int m = 0; m < 2; ++m)
#pragma unroll
        for (int n = 0; n < 4; ++n) acc[m][n] = MFMA16(am[m], bn[n], acc[m][n]);
    }
#pragma unroll
    for (int m = 0; m < 2; ++m)
#pragma unroll
      for (int r = 0; r < 4; ++r) {
        int o = 32 * wid + 16 * m + 4 * g + r;
        float bias = b2[o];
#pragma unroll
        for (int n = 0; n < 4; ++n) {
          int pos = n0 + 16 * n + l15;
          size_t idx = ((size_t)b * 256 + o) * 4096 + pos;
          out[idx] = acc[m][n][r] + bias + x[idx];
        }
      }
  }
}

// ---- workspace layout (bytes) ---------------------------------------------
#define WS_XT 0u          //  8,388,608  xT  [4][4096][256] bf16
#define WS_QT 8388608u    //  2,097,152  Qt  [4][4096][64]  bf16
#define WS_KT 10485760u   //  2,097,152  Kt  [4][4096][64]  bf16
#define WS_VC 12582912u   //  8,388,608  Vc  [4][256][4096] bf16
#define WS_ATT 20971520u  //  8,388,608  attT[4][4096][256] bf16
#define WS_RS 29360128u   //     65,536  (unused since R14)
#define WS_WQ 29425664u   //     32,768
#define WS_WK 29458432u   //     32,768
#define WS_WV 29491200u   //    131,072
#define WS_W1 29622272u   //    131,072
#define WS_W2 29753344u   //    131,072   (end: 29,884,416)

extern "C" void kernel_launch(void* const* d_in, const int* in_sizes, int n_in,
                              void* d_out, int out_size, void* d_ws, size_t ws_size,
                              hipStream_t stream) {
  (void)in_sizes; (void)n_in; (void)out_size; (void)ws_size;
  const float* x  = (const float*)d_in[0];
  const float* WQ = (const float*)d_in[1];
  const float* bQ = (const float*)d_in[2];
  const float* WK = (const float*)d_in[3];
  const float* bK = (const float*)d_in[4];
  const float* WV = (const float*)d_in[5];
  const float* bV = (const float*)d_in[6];
  const float* PE = (const float*)d_in[7];
  const float* W1 = (const float*)d_in[8];
  const float* b1 = (const float*)d_in[9];
  const float* W2 = (const float*)d_in[10];
  const float* b2 = (const float*)d_in[11];
  float* out = (float*)d_out;
  char* ws = (char*)d_ws;

  u16* xT   = (u16*)(ws + WS_XT);
  u16* Qt   = (u16*)(ws + WS_QT);
  u16* Kt   = (u16*)(ws + WS_KT);
  u16* Vc   = (u16*)(ws + WS_VC);
  u16* attT = (u16*)(ws + WS_ATT);
  u16* wqB  = (u16*)(ws + WS_WQ);
  u16* wkB  = (u16*)(ws + WS_WK);
  u16* wvB  = (u16*)(ws + WS_WV);
  u16* w1B  = (u16*)(ws + WS_W1);
  u16* w2B  = (u16*)(ws + WS_W2);

  k_convert<<<896, 256, 0, stream>>>(WQ, WK, WV, W1, W2, wqB, wkB, wvB, w1B, w2B);
  k_transpose<<<dim3(64, 4, 4), 256, 0, stream>>>(x, xT);
  k_proj<<<512, 256, 0, stream>>>(xT, wqB, wkB, wvB, bQ, bK, bV, PE, Qt, Kt, Vc);
  k_colsum<<<256, 512, 0, stream>>>(Qt, Kt, Vc);
  k_attn<<<512, 256, 0, stream>>>(Qt, Kt, Vc, attT);
  k_mlp<<<256, 512, 0, stream>>>(attT, w1B, b1, w2B, b2, x, out);
}